// Round 5
// baseline (117.800 us; speedup 1.0000x reference)
//
#include <hip/hip_runtime.h>
#include <hip/hip_bf16.h>

#define BB 4
#define CCH 128
#define C2 256
#define OO 128
#define NVOX 32768            // 32*32*32 voxels per (b, channel)
#define NTOT (BB*NVOX)        // reduction count per output channel
#define NGB 1024              // gemm blocks (= stats partials)

typedef __attribute__((ext_vector_type(4))) float f32x4;
typedef __attribute__((ext_vector_type(8))) short s16x8;
typedef __attribute__((ext_vector_type(4))) unsigned int u32x4;
typedef unsigned int u32;
typedef unsigned short u16;

// XOR swizzle on the 16B column-block index, keyed by row. Bijective per row. (GEMM)
#define SWZ(r) ((((r)>>3) ^ (r)) & 7)

__device__ __forceinline__ float bf2f(short s){
  union { u32 i; float f; } cv; cv.i = ((u32)(u16)s) << 16; return cv.f;
}
__device__ __forceinline__ short f2bf(float f){
  union { __hip_bfloat16 h; short s; } cv; cv.h = __float2bfloat16(f); return cv.s;
}
__device__ __forceinline__ u32 pack2(float a, float b){
  return ((u32)(u16)f2bf(a)) | (((u32)(u16)f2bf(b)) << 16);
}
__device__ __forceinline__ float ulo(u32 r){
  union { u32 i; float f; } cv; cv.i = r << 16; return cv.f;
}
__device__ __forceinline__ float uhi(u32 r){
  union { u32 i; float f; } cv; cv.i = r & 0xffff0000u; return cv.f;
}
__device__ __forceinline__ float bfr(float f){ return bf2f(f2bf(f)); }  // bf16 round

// ---- K0: conv_w fp32 -> bf16 -------------------------------------------------
__global__ __launch_bounds__(256) void k_convw(const float* __restrict__ w, short* __restrict__ wb){
  int i = blockIdx.x*256 + threadIdx.x;
  wb[i] = f2bf(w[i]);
}

// ---- K1: per-(b,c) parity-line tables (min1,min2), no LDS, pure streaming ----
// tw[bc][h][pw][d] : min1/min2 over all w of parity pw (bf16-rounded values)
// th[bc][ph][w][d] : min1/min2 over all h of parity ph
// min-excluding-self recovered later via me = (x==min1)?min2:min1
__global__ __launch_bounds__(1024) void k_tab(const float* __restrict__ x,
                                              u32* __restrict__ tw, u32* __restrict__ th){
  int t = threadIdx.x;
  u32 bc = blockIdx.x;
  const float* __restrict__ src = x + (size_t)bc*NVOX;
  int a = t >> 5, d = t & 31;
  // W-pass: thread (h=a, d)
  {
    float m1[2] = {1e30f,1e30f}, m2[2] = {1e30f,1e30f};
    #pragma unroll
    for(int w=0;w<32;w++){
      float v = bfr(src[a*1024 + w*32 + d]);
      int p = w & 1;
      m2[p] = fminf(m2[p], fmaxf(m1[p], v));
      m1[p] = fminf(m1[p], v);
    }
    u32* r = tw + (size_t)bc*2048 + a*64;
    r[d]      = pack2(m1[0], m2[0]);
    r[32 + d] = pack2(m1[1], m2[1]);
  }
  // H-pass: thread (w=a, d)  (same 128KB, L2-hot)
  {
    float m1[2] = {1e30f,1e30f}, m2[2] = {1e30f,1e30f};
    #pragma unroll
    for(int h=0;h<32;h++){
      float v = bfr(src[h*1024 + a*32 + d]);
      int p = h & 1;
      m2[p] = fminf(m2[p], fmaxf(m1[p], v));
      m1[p] = fminf(m1[p], v);
    }
    u32* r = th + (size_t)bc*2048 + a*32;
    r[d]        = pack2(m1[0], m2[0]);
    r[1024 + d] = pack2(m1[1], m2[1]);
  }
}

// ---- K2: fused x_j + GEMM + BN partials --------------------------------------
// kc0 tile = bf16(x) staged from fp32 (L3-hot). After MFMA-kc0, in-place column
// transform computes x_j (D-min inline, W/H-min from tables). MFMA-kc1 on it.
__global__ __launch_bounds__(256) void k_gemm(const float* __restrict__ x, const short* __restrict__ wb,
                                              const u32* __restrict__ tw, const u32* __restrict__ th,
                                              short* __restrict__ y, float* __restrict__ part){
  __shared__ __align__(16) char lds[32768];      // [v 128][c 128] bf16, swizzled blocks
  u32 blk = blockIdx.x;
  u32 vblk = blk & 255, b = blk >> 8;
  u32 vbase = vblk * 128;
  const float* __restrict__ xb = x + (size_t)b*CCH*NVOX + vbase;
  int t = threadIdx.x;
  int wave = t >> 6, lane = t & 63;
  int wr = wave >> 1, wc = wave & 1;    // o-half, v-half
  int l15 = lane & 15, l4 = lane >> 4;
  f32x4 acc[4][4];
  #pragma unroll
  for(int mt=0;mt<4;mt++)
    #pragma unroll
    for(int nt=0;nt<4;nt++) acc[mt][nt] = (f32x4){0.f,0.f,0.f,0.f};

  // ---- stage kc0: fp32 x -> bf16 pairs, coalesced ----
  {
    int v0  = (t & 15) * 8;
    int cb2 = 2 * (t >> 4);
    #pragma unroll
    for(int q=0;q<4;q++){
      int c = cb2 + 32*q;
      const float* pe = xb + (size_t)c*NVOX;
      const float* po = pe + NVOX;
      f32x4 e0 = *(const f32x4*)(pe + v0), e1 = *(const f32x4*)(pe + v0 + 4);
      f32x4 o0 = *(const f32x4*)(po + v0), o1 = *(const f32x4*)(po + v0 + 4);
      #pragma unroll
      for(int e=0;e<4;e++){
        int v = v0 + e;
        *(u32*)(lds + v*256 + ((((c>>3) ^ SWZ(v))<<4) | ((c&7)<<1))) = pack2(e0[e], o0[e]);
        int v2 = v0 + 4 + e;
        *(u32*)(lds + v2*256 + ((((c>>3) ^ SWZ(v2))<<4) | ((c&7)<<1))) = pack2(e1[e], o1[e]);
      }
    }
  }
  __syncthreads();

  // ---- MFMA kc0 (A = W[:,0:128]) ----
  #pragma unroll
  for(int ks=0;ks<4;ks++){
    int kk = ks*32 + l4*8;
    s16x8 afrag[4], bfrag[4];
    #pragma unroll
    for(int nt=0;nt<4;nt++){
      int vloc = wc*64 + nt*16 + l15;
      bfrag[nt] = *(const s16x8*)(lds + vloc*256 + (((kk>>3) ^ SWZ(vloc))<<4));
    }
    #pragma unroll
    for(int mt=0;mt<4;mt++){
      int o = wr*64 + mt*16 + l15;
      afrag[mt] = *(const s16x8*)(wb + o*C2 + kk);
    }
    #pragma unroll
    for(int mt=0;mt<4;mt++)
      #pragma unroll
      for(int nt=0;nt<4;nt++)
        acc[mt][nt] = __builtin_amdgcn_mfma_f32_16x16x32_bf16(afrag[mt], bfrag[nt], acc[mt][nt], 0,0,0);
  }
  __syncthreads();

  // ---- in-place transform: tile <- x_j (per column = one d-line per c-pair) --
  {
    int cp = t >> 2, line = t & 3;       // 64 c-pairs x 4 d-lines
    int ce = 2*cp;
    int h  = vbase >> 10;
    int w  = ((vbase >> 5) & 31) + line;
    // pass 1: D-axis (min1,min2) per parity, both channels of the pair
    float m1e[2]={1e30f,1e30f}, m2e[2]={1e30f,1e30f};
    float m1o[2]={1e30f,1e30f}, m2o[2]={1e30f,1e30f};
    #pragma unroll
    for(int i=0;i<32;i++){
      int v = line*32 + i;
      u32 pr = *(const u32*)(lds + v*256 + ((((ce>>3) ^ SWZ(v))<<4) | ((ce&7)<<1)));
      float xe = ulo(pr), xo = uhi(pr);
      int p = i & 1;
      m2e[p] = fminf(m2e[p], fmaxf(m1e[p], xe)); m1e[p] = fminf(m1e[p], xe);
      m2o[p] = fminf(m2o[p], fmaxf(m1o[p], xo)); m1o[p] = fminf(m1o[p], xo);
    }
    // pass 2: combine with W/H tables (L2-hot), write x_j back in place
    size_t bce = (size_t)(b*CCH + ce);
    const u32* twE = tw + bce*2048 + h*64 + (w&1)*32;
    const u32* thE = th + bce*2048 + (h&1)*1024 + w*32;
    #pragma unroll
    for(int g=0;g<8;g++){
      u32x4 we = *(const u32x4*)(twE + g*4);
      u32x4 wo = *(const u32x4*)(twE + 2048 + g*4);
      u32x4 he = *(const u32x4*)(thE + g*4);
      u32x4 ho = *(const u32x4*)(thE + 2048 + g*4);
      #pragma unroll
      for(int i=0;i<4;i++){
        int dd = g*4 + i, v = line*32 + dd, p = dd & 1;
        char* ad = lds + v*256 + ((((ce>>3) ^ SWZ(v))<<4) | ((ce&7)<<1));
        u32 pr = *(u32*)ad;
        float xe = ulo(pr), xo = uhi(pr);
        float mDe = (xe == m1e[p]) ? m2e[p] : m1e[p];
        float mDo = (xo == m1o[p]) ? m2o[p] : m1o[p];
        float w1e = ulo(we[i]); float mWe = (xe == w1e) ? uhi(we[i]) : w1e;
        float w1o = ulo(wo[i]); float mWo = (xo == w1o) ? uhi(wo[i]) : w1o;
        float h1e = ulo(he[i]); float mHe = (xe == h1e) ? uhi(he[i]) : h1e;
        float h1o = ulo(ho[i]); float mHo = (xo == h1o) ? uhi(ho[i]) : h1o;
        float je = fmaxf(0.f, xe - fminf(mDe, fminf(mWe, mHe)));
        float jo = fmaxf(0.f, xo - fminf(mDo, fminf(mWo, mHo)));
        *(u32*)ad = pack2(je, jo);
      }
    }
  }
  __syncthreads();

  // ---- MFMA kc1 (A = W[:,128:256]) ----
  #pragma unroll
  for(int ks=0;ks<4;ks++){
    int kk = ks*32 + l4*8;
    s16x8 afrag[4], bfrag[4];
    #pragma unroll
    for(int nt=0;nt<4;nt++){
      int vloc = wc*64 + nt*16 + l15;
      bfrag[nt] = *(const s16x8*)(lds + vloc*256 + (((kk>>3) ^ SWZ(vloc))<<4));
    }
    #pragma unroll
    for(int mt=0;mt<4;mt++){
      int o = wr*64 + mt*16 + l15;
      afrag[mt] = *(const s16x8*)(wb + o*C2 + 128 + kk);
    }
    #pragma unroll
    for(int mt=0;mt<4;mt++)
      #pragma unroll
      for(int nt=0;nt<4;nt++)
        acc[mt][nt] = __builtin_amdgcn_mfma_f32_16x16x32_bf16(afrag[mt], bfrag[nt], acc[mt][nt], 0,0,0);
  }

  // ---- Epilogue: acc -> LDS [o][v] bf16 (swizzled) -> coalesced stores -------
  // C/D: col = lane&15 (v), row = (lane>>4)*4 + r (o)   [m89-verified]
  __syncthreads();
  #pragma unroll
  for(int mt=0;mt<4;mt++){
    #pragma unroll
    for(int nt=0;nt<4;nt++){
      int vcol = wc*64 + nt*16 + l15;
      #pragma unroll
      for(int r=0;r<4;r++){
        int o = wr*64 + mt*16 + l4*4 + r;
        *(short*)(lds + o*256 + ((((vcol>>3) ^ SWZ(o))<<4) | ((vcol&7)<<1))) = f2bf(acc[mt][nt][r]);
      }
    }
  }
  __syncthreads();
  short* __restrict__ yb = y + (size_t)b*OO*NVOX + vbase;
  #pragma unroll
  for(int q=0;q<8;q++){
    int p = t + q*256;
    int o = p >> 4, vs = (p & 15) * 8;
    s16x8 val = *(const s16x8*)(lds + o*256 + ((((vs>>3) ^ SWZ(o))<<4)));
    *(s16x8*)(yb + (size_t)o*NVOX + vs) = val;
  }

  // ---- Fused BN partial stats from the same LDS tile -------------------------
  {
    int o = t >> 1, vh = t & 1;
    float sm = 0.f, ss = 0.f;
    #pragma unroll
    for(int k=0;k<8;k++){
      int vs = vh*64 + k*8;
      s16x8 val = *(const s16x8*)(lds + o*256 + ((((vs>>3) ^ SWZ(o))<<4)));
      #pragma unroll
      for(int e=0;e<8;e++){ float f = bf2f(val[e]); sm += f; ss += f*f; }
    }
    sm += __shfl_xor(sm, 1);
    ss += __shfl_xor(ss, 1);
    if(vh == 0){
      float* pp = part + ((size_t)blk*OO + o)*2;
      pp[0] = sm; pp[1] = ss;
    }
  }
}

// ---- K3: finalize stats from 1024 per-block partials -------------------------
__global__ __launch_bounds__(256) void k_statsf(const float* __restrict__ part, float* __restrict__ stats){
  int o = blockIdx.x, t = threadIdx.x;
  float sm = 0.f, ss = 0.f;
  #pragma unroll
  for(int k=0;k<4;k++){
    int blk = t + k*256;
    const float* pp = part + ((size_t)blk*OO + o)*2;
    sm += pp[0]; ss += pp[1];
  }
  __shared__ float rs[256], rss[256];
  rs[t] = sm; rss[t] = ss;
  __syncthreads();
  for(int k=128;k>0;k>>=1){
    if(t<k){ rs[t]+=rs[t+k]; rss[t]+=rss[t+k]; }
    __syncthreads();
  }
  if(t==0){
    float inv = 1.0f/(float)NTOT;
    float mean = rs[0]*inv;
    float var = rss[0]*inv - mean*mean;
    stats[2*o]   = mean;
    stats[2*o+1] = rsqrtf(var + 1e-5f);
  }
}

// ---- K4: BN scale-shift + exact-erf GELU ------------------------------------
__global__ __launch_bounds__(256) void k_bngelu(const short* __restrict__ y, const float* __restrict__ stats,
                                                const float* __restrict__ gamma, const float* __restrict__ beta,
                                                float* __restrict__ out){
  size_t base = ((size_t)blockIdx.x*256 + threadIdx.x)*8;
  int o = (int)((base >> 15) & 127);
  float mean = stats[2*o], rstd = stats[2*o+1];
  float g  = gamma[o]*rstd;
  float be = beta[o] - mean*g;
  s16x8 u = *(const s16x8*)(y + base);
  f32x4 r0, r1;
  #pragma unroll
  for(int e=0;e<8;e++){
    float yn = bf2f(u[e])*g + be;
    float ge = 0.5f*yn*(1.0f + erff(yn*0.70710678118654752f));
    if(e<4) r0[e] = ge; else r1[e-4] = ge;
  }
  *(f32x4*)(out + base)     = r0;
  *(f32x4*)(out + base + 4) = r1;
}

extern "C" void kernel_launch(void* const* d_in, const int* in_sizes, int n_in,
                              void* d_out, int out_size, void* d_ws, size_t ws_size,
                              hipStream_t stream) {
  (void)in_sizes; (void)n_in; (void)out_size; (void)ws_size;
  const float* x     = (const float*)d_in[0];
  const float* cw    = (const float*)d_in[1];
  // d_in[2] = conv_b: mathematically cancels in training-mode BatchNorm
  const float* gamma = (const float*)d_in[3];
  const float* beta  = (const float*)d_in[4];
  float* out = (float*)d_out;

  char* ws = (char*)d_ws;
  short* wb    = (short*)ws;                                   // 64 KB bf16 W
  short* y     = (short*)(ws + 65536);                         // 33.5 MB bf16 y
  float* stats = (float*)(ws + 65536 + (size_t)BB*OO*NVOX*2);  // 1 KB
  float* part  = stats + 256;                                  // 1 MB partials
  u32* tw = (u32*)d_out;                                       // 4 MB W-table (scratch in d_out)
  u32* th = tw + (size_t)512*2048;                             // 4 MB H-table

  k_convw <<<dim3((OO*C2)/256),     dim3(256), 0, stream>>>(cw, wb);
  k_tab   <<<dim3(BB*CCH),         dim3(1024), 0, stream>>>(x, tw, th);
  k_gemm  <<<dim3(BB*(NVOX/128)),  dim3(256), 0, stream>>>(x, wb, tw, th, y, part);
  k_statsf<<<dim3(OO),             dim3(256), 0, stream>>>(part, stats);
  k_bngelu<<<dim3((NTOT*OO)/2048), dim3(256), 0, stream>>>(y, stats, gamma, beta, out);
}

// Round 6
// 89.586 us; speedup vs baseline: 1.3149x; 1.3149x over previous
//
#include <hip/hip_runtime.h>
#include <hip/hip_bf16.h>

#define BB 4
#define CCH 128
#define C2 256
#define OO 128
#define NVOX 32768            // 32*32*32 voxels per (b, channel)
#define NTOT (BB*NVOX)        // reduction count per output channel
#define NGB 1024              // gemm blocks (= stats partials)

typedef __attribute__((ext_vector_type(4))) float f32x4;
typedef __attribute__((ext_vector_type(8))) short s16x8;
typedef __attribute__((ext_vector_type(4))) unsigned int u32x4;
typedef unsigned int u32;
typedef unsigned short u16;

// XOR swizzle on the 16B column-block index, keyed by row. Bijective per row. (GEMM)
#define SWZ(r) ((((r)>>3) ^ (r)) & 7)

__device__ __forceinline__ float bf2f(short s){
  union { u32 i; float f; } cv; cv.i = ((u32)(u16)s) << 16; return cv.f;
}
__device__ __forceinline__ short f2bf(float f){
  union { __hip_bfloat16 h; short s; } cv; cv.h = __float2bfloat16(f); return cv.s;
}
__device__ __forceinline__ u32 pack2(float a, float b){
  return ((u32)(u16)f2bf(a)) | (((u32)(u16)f2bf(b)) << 16);
}
__device__ __forceinline__ float ulo(u32 r){
  union { u32 i; float f; } cv; cv.i = r << 16; return cv.f;
}
__device__ __forceinline__ float uhi(u32 r){
  union { u32 i; float f; } cv; cv.i = r & 0xffff0000u; return cv.f;
}
__device__ __forceinline__ float bfr(float f){ return bf2f(f2bf(f)); }  // bf16 round

// ---- K0: conv_w fp32 -> bf16 -------------------------------------------------
__global__ __launch_bounds__(256) void k_convw(const float* __restrict__ w, short* __restrict__ wb){
  int i = blockIdx.x*256 + threadIdx.x;
  wb[i] = f2bf(w[i]);
}

// ---- K1: per-(b,c) parity-line tables (min1,min2), no LDS, pure streaming ----
// tw[bc][h][pw][d] : min1/min2 over all w of parity pw (bf16-rounded values)
// th[bc][ph][w][d] : min1/min2 over all h of parity ph
// min-excluding-self recovered later via me = (x==min1)?min2:min1
__global__ __launch_bounds__(1024) void k_tab(const float* __restrict__ x,
                                              u32* __restrict__ tw, u32* __restrict__ th){
  int t = threadIdx.x;
  u32 bc = blockIdx.x;
  const float* __restrict__ src = x + (size_t)bc*NVOX;
  int a = t >> 5, d = t & 31;
  // W-pass: thread (h=a, d)
  {
    float m1[2] = {1e30f,1e30f}, m2[2] = {1e30f,1e30f};
    #pragma unroll
    for(int w=0;w<32;w++){
      float v = bfr(src[a*1024 + w*32 + d]);
      int p = w & 1;
      m2[p] = fminf(m2[p], fmaxf(m1[p], v));
      m1[p] = fminf(m1[p], v);
    }
    u32* r = tw + (size_t)bc*2048 + a*64;
    r[d]      = pack2(m1[0], m2[0]);
    r[32 + d] = pack2(m1[1], m2[1]);
  }
  // H-pass: thread (w=a, d)  (same 128KB, L2-hot)
  {
    float m1[2] = {1e30f,1e30f}, m2[2] = {1e30f,1e30f};
    #pragma unroll
    for(int h=0;h<32;h++){
      float v = bfr(src[h*1024 + a*32 + d]);
      int p = h & 1;
      m2[p] = fminf(m2[p], fmaxf(m1[p], v));
      m1[p] = fminf(m1[p], v);
    }
    u32* r = th + (size_t)bc*2048 + a*32;
    r[d]        = pack2(m1[0], m2[0]);
    r[1024 + d] = pack2(m1[1], m2[1]);
  }
}

// ---- K2: fused x_j + GEMM + BN partials --------------------------------------
// Stage phase (no barriers): per q, load fp32 x pair-channels, pack bf16 ->
// tileX; compute D-line (min1,min2) in regs + 2x shfl_xor combine; read W/H
// tables (L2-hot); compute x_j in regs -> tileJ. ONE barrier, then all 32
// MFMAs (kc0 on tileX, kc1 on tileJ), then epilogue via LDS + stats partials.
__global__ __launch_bounds__(256) void k_gemm(const float* __restrict__ x, const short* __restrict__ wb,
                                              const u32* __restrict__ tw, const u32* __restrict__ th,
                                              short* __restrict__ y, float* __restrict__ part){
  __shared__ __align__(16) char lds[65536];      // tileX [v][c] + tileJ [v][c], swizzled
  char* ldsJ = lds + 32768;
  u32 blk = blockIdx.x;
  u32 vblk = blk & 255, b = blk >> 8;
  u32 vbase = vblk * 128;
  const float* __restrict__ xb = x + (size_t)b*CCH*NVOX + vbase;
  int t = threadIdx.x;
  int wave = t >> 6, lane = t & 63;
  int wr = wave >> 1, wc = wave & 1;    // o-half, v-half
  int l15 = lane & 15, l4 = lane >> 4;

  // ---- stage: x -> tileX, x_j -> tileJ, all register-resident ----
  {
    int v0   = (t & 15) * 8;            // 8 consecutive voxels (same d-line)
    int line = (t & 15) >> 2;           // 0..3
    int d0   = (t & 3) * 8;             // 0,8,16,24 (even)
    int cb2  = 2 * (t >> 4);
    int h  = vbase >> 10;
    int w  = ((vbase >> 5) & 31) + line;
    #pragma unroll
    for(int q=0;q<4;q++){
      int c = cb2 + 32*q;               // channels (c, c+1)
      const float* pe = xb + (size_t)c*NVOX + v0;
      const float* po = pe + NVOX;
      f32x4 e0 = *(const f32x4*)(pe),     e1 = *(const f32x4*)(pe + 4);
      f32x4 o0 = *(const f32x4*)(po),     o1 = *(const f32x4*)(po + 4);
      u32 pr[8];
      #pragma unroll
      for(int e=0;e<4;e++){
        pr[e]   = pack2(e0[e], o0[e]);
        pr[4+e] = pack2(e1[e], o1[e]);
      }
      #pragma unroll
      for(int e=0;e<8;e++){
        int v = v0 + e;
        *(u32*)(lds + v*256 + ((((c>>3) ^ SWZ(v))<<4) | ((c&7)<<1))) = pr[e];
      }
      // D-axis (min1,min2) per parity, both channels, over own 8 d's
      float m1e[2]={1e30f,1e30f}, m2e[2]={1e30f,1e30f};
      float m1o[2]={1e30f,1e30f}, m2o[2]={1e30f,1e30f};
      #pragma unroll
      for(int e=0;e<8;e++){
        int p = e & 1;
        float xe = ulo(pr[e]), xo = uhi(pr[e]);
        m2e[p] = fminf(m2e[p], fmaxf(m1e[p], xe)); m1e[p] = fminf(m1e[p], xe);
        m2o[p] = fminf(m2o[p], fmaxf(m1o[p], xo)); m1o[p] = fminf(m1o[p], xo);
      }
      // combine across the 4 threads of this d-line (lanes ^1, ^2)
      #pragma unroll
      for(int mk=1;mk<=2;mk<<=1){
        #pragma unroll
        for(int p=0;p<2;p++){
          float b1, b2;
          b1 = __shfl_xor(m1e[p], mk); b2 = __shfl_xor(m2e[p], mk);
          m2e[p] = fminf(fmaxf(m1e[p], b1), fminf(m2e[p], b2));
          m1e[p] = fminf(m1e[p], b1);
          b1 = __shfl_xor(m1o[p], mk); b2 = __shfl_xor(m2o[p], mk);
          m2o[p] = fminf(fmaxf(m1o[p], b1), fminf(m2o[p], b2));
          m1o[p] = fminf(m1o[p], b1);
        }
      }
      // W/H tables for (c, c+1), this (h,w), d0..d0+7
      size_t bce = ((size_t)b*CCH + c)*2048;
      const u32* twE = tw + bce + h*64 + (w&1)*32 + d0;
      const u32* thE = th + bce + (h&1)*1024 + w*32 + d0;
      u32x4 we0 = *(const u32x4*)(twE),        we1 = *(const u32x4*)(twE + 4);
      u32x4 wo0 = *(const u32x4*)(twE + 2048), wo1 = *(const u32x4*)(twE + 2052);
      u32x4 he0 = *(const u32x4*)(thE),        he1 = *(const u32x4*)(thE + 4);
      u32x4 ho0 = *(const u32x4*)(thE + 2048), ho1 = *(const u32x4*)(thE + 2052);
      #pragma unroll
      for(int e=0;e<8;e++){
        int p = e & 1;
        float xe = ulo(pr[e]), xo = uhi(pr[e]);
        u32 we = (e<4) ? we0[e] : we1[e-4];
        u32 wo = (e<4) ? wo0[e] : wo1[e-4];
        u32 he = (e<4) ? he0[e] : he1[e-4];
        u32 ho = (e<4) ? ho0[e] : ho1[e-4];
        float mDe = (xe == m1e[p]) ? m2e[p] : m1e[p];
        float mDo = (xo == m1o[p]) ? m2o[p] : m1o[p];
        float w1e = ulo(we); float mWe = (xe == w1e) ? uhi(we) : w1e;
        float w1o = ulo(wo); float mWo = (xo == w1o) ? uhi(wo) : w1o;
        float h1e = ulo(he); float mHe = (xe == h1e) ? uhi(he) : h1e;
        float h1o = ulo(ho); float mHo = (xo == h1o) ? uhi(ho) : h1o;
        float je = fmaxf(0.f, xe - fminf(mDe, fminf(mWe, mHe)));
        float jo = fmaxf(0.f, xo - fminf(mDo, fminf(mWo, mHo)));
        int v = v0 + e;
        *(u32*)(ldsJ + v*256 + ((((c>>3) ^ SWZ(v))<<4) | ((c&7)<<1))) = pack2(je, jo);
      }
    }
  }
  __syncthreads();

  // ---- MFMA: kc0 on tileX (W[:,0:128]), kc1 on tileJ (W[:,128:256]) ----
  f32x4 acc[4][4];
  #pragma unroll
  for(int mt=0;mt<4;mt++)
    #pragma unroll
    for(int nt=0;nt<4;nt++) acc[mt][nt] = (f32x4){0.f,0.f,0.f,0.f};
  #pragma unroll
  for(int kc=0;kc<2;kc++){
    const char* tile = (kc == 0) ? lds : ldsJ;
    #pragma unroll
    for(int ks=0;ks<4;ks++){
      int kk = ks*32 + l4*8;
      s16x8 afrag[4], bfrag[4];
      #pragma unroll
      for(int nt=0;nt<4;nt++){
        int vloc = wc*64 + nt*16 + l15;
        bfrag[nt] = *(const s16x8*)(tile + vloc*256 + (((kk>>3) ^ SWZ(vloc))<<4));
      }
      #pragma unroll
      for(int mt=0;mt<4;mt++){
        int o = wr*64 + mt*16 + l15;
        afrag[mt] = *(const s16x8*)(wb + o*C2 + kc*128 + kk);
      }
      #pragma unroll
      for(int mt=0;mt<4;mt++)
        #pragma unroll
        for(int nt=0;nt<4;nt++)
          acc[mt][nt] = __builtin_amdgcn_mfma_f32_16x16x32_bf16(afrag[mt], bfrag[nt], acc[mt][nt], 0,0,0);
    }
  }

  // ---- Epilogue: acc -> LDS [o][v] bf16 (swizzled) -> coalesced stores -------
  // C/D: col = lane&15 (v), row = (lane>>4)*4 + r (o)   [m89-verified]
  __syncthreads();
  #pragma unroll
  for(int mt=0;mt<4;mt++){
    #pragma unroll
    for(int nt=0;nt<4;nt++){
      int vcol = wc*64 + nt*16 + l15;
      #pragma unroll
      for(int r=0;r<4;r++){
        int o = wr*64 + mt*16 + l4*4 + r;
        *(short*)(lds + o*256 + ((((vcol>>3) ^ SWZ(o))<<4) | ((vcol&7)<<1))) = f2bf(acc[mt][nt][r]);
      }
    }
  }
  __syncthreads();
  short* __restrict__ yb = y + (size_t)b*OO*NVOX + vbase;
  #pragma unroll
  for(int q=0;q<8;q++){
    int p = t + q*256;
    int o = p >> 4, vs = (p & 15) * 8;
    s16x8 val = *(const s16x8*)(lds + o*256 + ((((vs>>3) ^ SWZ(o))<<4)));
    *(s16x8*)(yb + (size_t)o*NVOX + vs) = val;
  }

  // ---- Fused BN partial stats from the same LDS tile -------------------------
  {
    int o = t >> 1, vh = t & 1;
    float sm = 0.f, ss = 0.f;
    #pragma unroll
    for(int k=0;k<8;k++){
      int vs = vh*64 + k*8;
      s16x8 val = *(const s16x8*)(lds + o*256 + ((((vs>>3) ^ SWZ(o))<<4)));
      #pragma unroll
      for(int e=0;e<8;e++){ float f = bf2f(val[e]); sm += f; ss += f*f; }
    }
    sm += __shfl_xor(sm, 1);
    ss += __shfl_xor(ss, 1);
    if(vh == 0){
      float* pp = part + ((size_t)blk*OO + o)*2;
      pp[0] = sm; pp[1] = ss;
    }
  }
}

// ---- K3: finalize stats from 1024 per-block partials -------------------------
__global__ __launch_bounds__(256) void k_statsf(const float* __restrict__ part, float* __restrict__ stats){
  int o = blockIdx.x, t = threadIdx.x;
  float sm = 0.f, ss = 0.f;
  #pragma unroll
  for(int k=0;k<4;k++){
    int blk = t + k*256;
    const float* pp = part + ((size_t)blk*OO + o)*2;
    sm += pp[0]; ss += pp[1];
  }
  __shared__ float rs[256], rss[256];
  rs[t] = sm; rss[t] = ss;
  __syncthreads();
  for(int k=128;k>0;k>>=1){
    if(t<k){ rs[t]+=rs[t+k]; rss[t]+=rss[t+k]; }
    __syncthreads();
  }
  if(t==0){
    float inv = 1.0f/(float)NTOT;
    float mean = rs[0]*inv;
    float var = rss[0]*inv - mean*mean;
    stats[2*o]   = mean;
    stats[2*o+1] = rsqrtf(var + 1e-5f);
  }
}

// ---- K4: BN scale-shift + exact-erf GELU ------------------------------------
__global__ __launch_bounds__(256) void k_bngelu(const short* __restrict__ y, const float* __restrict__ stats,
                                                const float* __restrict__ gamma, const float* __restrict__ beta,
                                                float* __restrict__ out){
  size_t base = ((size_t)blockIdx.x*256 + threadIdx.x)*8;
  int o = (int)((base >> 15) & 127);
  float mean = stats[2*o], rstd = stats[2*o+1];
  float g  = gamma[o]*rstd;
  float be = beta[o] - mean*g;
  s16x8 u = *(const s16x8*)(y + base);
  f32x4 r0, r1;
  #pragma unroll
  for(int e=0;e<8;e++){
    float yn = bf2f(u[e])*g + be;
    float ge = 0.5f*yn*(1.0f + erff(yn*0.70710678118654752f));
    if(e<4) r0[e] = ge; else r1[e-4] = ge;
  }
  *(f32x4*)(out + base)     = r0;
  *(f32x4*)(out + base + 4) = r1;
}

extern "C" void kernel_launch(void* const* d_in, const int* in_sizes, int n_in,
                              void* d_out, int out_size, void* d_ws, size_t ws_size,
                              hipStream_t stream) {
  (void)in_sizes; (void)n_in; (void)out_size; (void)ws_size;
  const float* x     = (const float*)d_in[0];
  const float* cw    = (const float*)d_in[1];
  // d_in[2] = conv_b: mathematically cancels in training-mode BatchNorm
  const float* gamma = (const float*)d_in[3];
  const float* beta  = (const float*)d_in[4];
  float* out = (float*)d_out;

  char* ws = (char*)d_ws;
  short* wb    = (short*)ws;                                   // 64 KB bf16 W
  short* y     = (short*)(ws + 65536);                         // 33.5 MB bf16 y
  float* stats = (float*)(ws + 65536 + (size_t)BB*OO*NVOX*2);  // 1 KB
  float* part  = stats + 256;                                  // 1 MB partials
  u32* tw = (u32*)d_out;                                       // 4 MB W-table (scratch in d_out)
  u32* th = tw + (size_t)512*2048;                             // 4 MB H-table

  k_convw <<<dim3((OO*C2)/256),     dim3(256), 0, stream>>>(cw, wb);
  k_tab   <<<dim3(BB*CCH),         dim3(1024), 0, stream>>>(x, tw, th);
  k_gemm  <<<dim3(BB*(NVOX/128)),  dim3(256), 0, stream>>>(x, wb, tw, th, y, part);
  k_statsf<<<dim3(OO),             dim3(256), 0, stream>>>(part, stats);
  k_bngelu<<<dim3((NTOT*OO)/2048), dim3(256), 0, stream>>>(y, stats, gamma, beta, out);
}